// Round 5
// baseline (2334.911 us; speedup 1.0000x reference)
//
#include <hip/hip_runtime.h>
#include <cstdint>

// Problem constants
#define D_DIM  2048
#define T_DIM  4096
#define B_DIM  2
#define M_DIM  8192   // B*T
#define DG_DIM 2048
#define N2_DIM 8192   // D*W (W=4)
#define K_DIM  2048
#define NT_TILES (K_DIM / 64)   // 32 K-tiles of 64

typedef __bf16 bf16x8 __attribute__((ext_vector_type(8)));
typedef __bf16 bf16x4 __attribute__((ext_vector_type(4)));
typedef float  f32x4  __attribute__((ext_vector_type(4)));

__device__ __forceinline__ void gload_lds16(const void* g, void* l) {
  __builtin_amdgcn_global_load_lds(
      (__attribute__((address_space(1))) void*)g,
      (__attribute__((address_space(3))) void*)l, 16, 0, 0);
}

__device__ __forceinline__ float silu_f(float a) {
  return a / (1.f + __expf(-a));
}

// ---------------------------------------------------------------------------
// Casts
// ---------------------------------------------------------------------------
__global__ void cast_f32_bf16(const float* __restrict__ src,
                              __bf16* __restrict__ dst, int n4) {
  int i = blockIdx.x * blockDim.x + threadIdx.x;
  if (i >= n4) return;
  float4 v = ((const float4*)src)[i];
  bf16x4 o;
  o[0] = (__bf16)v.x; o[1] = (__bf16)v.y; o[2] = (__bf16)v.z; o[3] = (__bf16)v.w;
  ((bf16x4*)dst)[i] = o;
}

// w2 row-permutation: GEMM column c = n0 + wn*16 + j*64 + ln holds original
// row k = 4*d + j with d = 64*(c>>8) + 16*wn + ln, so each lane's 4
// j-fragments are the 4 taps of one d.
__global__ void cast_permute_w2(const float* __restrict__ src,
                                __bf16* __restrict__ dst, int n4) {
  int i = blockIdx.x * blockDim.x + threadIdx.x;
  if (i >= n4) return;
  const int row = i >> 9;            // dest row c (512 float4 per row of 2048)
  const int pos = i & 511;
  const int blk = row >> 8;          // 256-col tile
  const int cw  = row & 255;
  const int j   = cw >> 6;           // tap
  const int wn  = (cw >> 4) & 3;
  const int ln  = cw & 15;
  const int d   = blk * 64 + wn * 16 + ln;
  const int k   = 4 * d + j;         // original w2 row
  float4 v = ((const float4*)src)[(size_t)k * 512 + pos];
  bf16x4 o;
  o[0] = (__bf16)v.x; o[1] = (__bf16)v.y; o[2] = (__bf16)v.z; o[3] = (__bf16)v.w;
  ((bf16x4*)dst)[i] = o;
}

// ---------------------------------------------------------------------------
// 256x256 tile, BK=64, 8 waves (2M x 4N interleaved).  R5 structure:
// 2 barriers/tile + OVERLAPPED fragment prefetch: tile t+1's 24 ds_read_b128
// are interleaved with tile t's 64 MFMA in ONE scheduling region (double-
// buffered fragment registers), so the ~1500 cyc/CU of LDS read traffic
// hides under the ~2480 cyc MFMA shadow instead of sitting serial between
// barriers (R4's mistake).
//
// Body t (parity p = t&1; cur = frags(tile t), read in body t-1):
//   vmcnt(0)                 // only outstanding loads = tile t+1's 8 (depth-1)
//   barrier                  // publish tile t+1 LDS to all waves
//   stage tile t+2 (8 loads, parity p)
//   R8(aL') M16  R8(aH') M16  R4(b0') M16  R4(b1') M16   // pinned clusters
//   lgkmcnt(0); sched_barrier // frags(t+1) complete (rule-18 guard)
//   barrier                  // WAR publish: next body may overwrite parity p^1
//
// Hazards: RAW(t+1 LDS) by vmcnt+barrier; MFMA inputs (cur) ready since body
// t-1's lgkm+barrier; stages(t+2,parity p) overwrite regions whose last reads
// (cur, body t-1) completed before the last barrier; nxt reads hit parity p^1
// (disjoint from stages).  Clamped tail stages (s>=32) same pattern.
// NOTE (R2): natural dispatch only — XCD swizzle doubled FETCH (252->600MB).
// ---------------------------------------------------------------------------

struct Frags {
  bf16x8 aL[4][2];
  bf16x8 aH[4][2];
  bf16x8 b0[2][2];
  bf16x8 b1[2][2];
};

__device__ __forceinline__ void stage_unit(const __bf16* src, __bf16* sX,
                                           int s, int hf, int lq0) {
  const int k0 = (s < NT_TILES) ? (s * 64) : 0;       // clamp keeps vmcnt exact
  __bf16* dst = sX + ((s & 1) * 2 + hf) * 8192;
  const size_t goff = (size_t)hf * 128 * K_DIM + k0;
  gload_lds16(src + goff, dst + lq0);
  gload_lds16(src + goff + (size_t)64 * K_DIM, dst + lq0 + 4096);
}

__device__ __forceinline__ void read4(bf16x8 dst[4][2], const __bf16* base,
                                      const int off[4][2]) {
#pragma unroll
  for (int i = 0; i < 4; i++) {
    dst[i][0] = *(const bf16x8*)(base + off[i][0]);
    dst[i][1] = *(const bf16x8*)(base + off[i][1]);
  }
}

__device__ __forceinline__ void read2(bf16x8 dst[2][2], const __bf16* base,
                                      const int off[2][2]) {
#pragma unroll
  for (int j = 0; j < 2; j++) {
    dst[j][0] = *(const bf16x8*)(base + off[j][0]);
    dst[j][1] = *(const bf16x8*)(base + off[j][1]);
  }
}

__device__ __forceinline__ void mmaq(f32x4 acc[8][4], int ib, int jb,
                                     const bf16x8 a[4][2], const bf16x8 b[2][2]) {
  __builtin_amdgcn_s_setprio(1);
#pragma unroll
  for (int kk = 0; kk < 2; kk++)
#pragma unroll
    for (int i = 0; i < 4; i++)
#pragma unroll
      for (int j = 0; j < 2; j++)
        acc[ib + i][jb + j] = __builtin_amdgcn_mfma_f32_16x16x32_bf16(
            a[i][kk], b[j][kk], acc[ib + i][jb + j], 0, 0, 0);
  __builtin_amdgcn_s_setprio(0);
}

__device__ __forceinline__ void body_fn(f32x4 acc[8][4], Frags& cur, Frags& nxt,
                                        const __bf16* nA, const __bf16* nB,
                                        const __bf16* a_src, const __bf16* b_src,
                                        __bf16* sA, __bf16* sB, int s2, int lq0,
                                        const int aoff[4][2],
                                        const int boff[2][2]) {
  asm volatile("s_waitcnt vmcnt(0)" ::: "memory");
  __builtin_amdgcn_s_barrier();
  __builtin_amdgcn_sched_barrier(0);
  // stage tile t+2 (8 loads, issue-only)
  stage_unit(a_src, sA, s2, 0, lq0);
  stage_unit(a_src, sA, s2, 1, lq0);
  stage_unit(b_src, sB, s2, 0, lq0);
  stage_unit(b_src, sB, s2, 1, lq0);
  // interleaved: reads of tile t+1 fragments under tile t's MFMAs
  read4(nxt.aL, nA, aoff);
  __builtin_amdgcn_sched_barrier(0);
  mmaq(acc, 0, 0, cur.aL, cur.b0);
  __builtin_amdgcn_sched_barrier(0);
  read4(nxt.aH, nA + 8192, aoff);
  __builtin_amdgcn_sched_barrier(0);
  mmaq(acc, 4, 0, cur.aH, cur.b0);
  __builtin_amdgcn_sched_barrier(0);
  read2(nxt.b0, nB, boff);
  __builtin_amdgcn_sched_barrier(0);
  mmaq(acc, 0, 2, cur.aL, cur.b1);
  __builtin_amdgcn_sched_barrier(0);
  read2(nxt.b1, nB + 8192, boff);
  __builtin_amdgcn_sched_barrier(0);
  mmaq(acc, 4, 2, cur.aH, cur.b1);
  asm volatile("s_waitcnt lgkmcnt(0)" ::: "memory");
  __builtin_amdgcn_sched_barrier(0);
  __builtin_amdgcn_s_barrier();
}

__device__ __forceinline__ void gemm_core(const __bf16* __restrict__ A,
                                          const __bf16* __restrict__ B,
                                          int m0, int n0,
                                          __bf16* sA, __bf16* sB,
                                          f32x4 acc[8][4]) {
  constexpr int K = K_DIM;
  const int t    = threadIdx.x;       // 0..511
  const int lane = t & 63;
  const int wv   = t >> 6;
  const int wm   = wv >> 2;           // 0..1
  const int wn   = wv & 3;            // 0..3
  const int ln   = lane & 15, qd = lane >> 4;

  // Staging source: linear LDS dest chunk q = t; pre-swizzled global chunk
  // = (q&7) ^ (row&7).  Second gload per unit folded into stage_unit.
  const __bf16 *a_src, *b_src;
  int lq0;
  {
    int q = t, row = q >> 3, cg = (q & 7) ^ (row & 7);
    a_src = A + (size_t)(m0 + row) * K + cg * 8;
    b_src = B + (size_t)(n0 + row) * K + cg * 8;
    lq0 = q * 8;
  }

  // Fragment LDS offsets within a half-region (same for both halves).
  int aoff[4][2], boff[2][2];
#pragma unroll
  for (int i = 0; i < 4; i++)
#pragma unroll
    for (int kk = 0; kk < 2; kk++) {
      const int row = wm * 16 + i * 32 + ln;
      aoff[i][kk] = row * 64 + (((kk * 4 + qd) ^ (row & 7)) << 3);
    }
#pragma unroll
  for (int j = 0; j < 2; j++)
#pragma unroll
    for (int kk = 0; kk < 2; kk++) {
      const int row = j * 64 + wn * 16 + ln;
      boff[j][kk] = row * 64 + (((kk * 4 + qd) ^ (row & 7)) << 3);
    }

  const __bf16* A_p0 = sA;           const __bf16* A_p1 = sA + 16384;
  const __bf16* B_p0 = sB;           const __bf16* B_p1 = sB + 16384;

  Frags f0, f1;

  // Prologue: stage tile0 + tile1 fully (16 loads)
  stage_unit(a_src, sA, 0, 0, lq0);
  stage_unit(a_src, sA, 0, 1, lq0);
  stage_unit(b_src, sB, 0, 0, lq0);
  stage_unit(b_src, sB, 0, 1, lq0);
  stage_unit(a_src, sA, 1, 0, lq0);
  stage_unit(a_src, sA, 1, 1, lq0);
  stage_unit(b_src, sB, 1, 0, lq0);
  stage_unit(b_src, sB, 1, 1, lq0);
  asm volatile("s_waitcnt vmcnt(8)" ::: "memory");   // tile0 fully landed
  __builtin_amdgcn_s_barrier();
  __builtin_amdgcn_sched_barrier(0);
  // Read tile0's fragments into f0.
  read4(f0.aL, A_p0, aoff);
  read4(f0.aH, A_p0 + 8192, aoff);
  read2(f0.b0, B_p0, boff);
  read2(f0.b1, B_p0 + 8192, boff);
  asm volatile("s_waitcnt lgkmcnt(0)" ::: "memory");
  __builtin_amdgcn_sched_barrier(0);
  __builtin_amdgcn_s_barrier();

  for (int it = 0; it < NT_TILES / 2; ++it) {
    // body t = 2*it   : MFMA f0 (tile t), read f1 <- tile t+1 (parity 1)
    body_fn(acc, f0, f1, A_p1, B_p1, a_src, b_src, sA, sB, 2 * it + 2, lq0,
            aoff, boff);
    // body t = 2*it+1 : MFMA f1, read f0 <- tile t+2 (parity 0)
    body_fn(acc, f1, f0, A_p0, B_p0, a_src, b_src, sA, sB, 2 * it + 3, lq0,
            aoff, boff);
  }
  // Drain clamped tail staging before LDS is reused/deallocated.
  asm volatile("s_waitcnt vmcnt(0)" ::: "memory");
}

// ---------------------------------------------------------------------------
// GEMM1: H = silu(x_bf16 @ w1_bf16^T).  Natural dispatch (column-per-XCD).
// ---------------------------------------------------------------------------
__global__ __launch_bounds__(512) void gemm1_silu(
    const __bf16* __restrict__ A, const __bf16* __restrict__ B,
    __bf16* __restrict__ H) {
  __shared__ __bf16 sA[4 * 8192];
  __shared__ __bf16 sB[4 * 8192];
  const int m0 = blockIdx.y * 256, n0 = blockIdx.x * 256;
  f32x4 acc[8][4] = {};
  gemm_core(A, B, m0, n0, sA, sB, acc);

  const int lane = threadIdx.x & 63;
  const int wv   = threadIdx.x >> 6;
  const int wm   = wv >> 2, wn = wv & 3;
  const int ln   = lane & 15, qd = lane >> 4;
#pragma unroll
  for (int i = 0; i < 8; i++) {
    const int row0 = m0 + wm * 16 + i * 32 + qd * 4;
#pragma unroll
    for (int j = 0; j < 4; j++) {
      const int col = n0 + wn * 16 + j * 64 + ln;
#pragma unroll
      for (int r = 0; r < 4; r++)
        H[(size_t)(row0 + r) * DG_DIM + col] = (__bf16)silu_f(acc[i][j][r]);
    }
  }
}

// ---------------------------------------------------------------------------
// GEMM2 + fused causal depthwise conv + silu.  B = permuted w2; lane owns
// d = (n0>>2) + wn*16 + ln; its 4 j-fragments are taps w=0..3 of that d.
// Natural dispatch (R2 lesson).
// ---------------------------------------------------------------------------
__global__ __launch_bounds__(512) void gemm2_conv_silu(
    const __bf16* __restrict__ A, const __bf16* __restrict__ B,
    const float* __restrict__ b2, const float* __restrict__ x,
    float* __restrict__ out) {
  __shared__ __bf16 sA[4 * 8192];
  __shared__ __bf16 sB[4 * 8192];
  const int m0 = blockIdx.y * 256, n0 = blockIdx.x * 256;
  f32x4 acc[8][4] = {};
  gemm_core(A, B, m0, n0, sA, sB, acc);

  const int lane = threadIdx.x & 63;
  const int wv   = threadIdx.x >> 6;
  const int wm   = wv >> 2, wn = wv & 3;
  const int ln   = lane & 15, qd = lane >> 4;

  const int d = (n0 >> 2) + wn * 16 + ln;
  const float4 bias = *(const float4*)(b2 + 4 * d);

#pragma unroll
  for (int i = 0; i < 8; i++) {
    const int m_base = m0 + wm * 16 + i * 32 + qd * 4;   // + r
    const int b  = m_base >> 12;                          // T=4096
    const int tb = m_base & 4095;
    // taps: x[b, tb + s - 3, d] for s = r + j in [0,6]
    float xv[7];
#pragma unroll
    for (int s = 0; s < 7; s++) {
      const int tp = tb + s - 3;
      xv[s] = (tp >= 0) ? x[((size_t)((b << 12) + tp)) * D_DIM + d] : 0.f;
    }
#pragma unroll
    for (int r = 0; r < 4; r++) {
      float y = (acc[i][0][r] + bias.x) * xv[r + 0]
              + (acc[i][1][r] + bias.y) * xv[r + 1]
              + (acc[i][2][r] + bias.z) * xv[r + 2]
              + (acc[i][3][r] + bias.w) * xv[r + 3];
      out[(size_t)(m_base + r) * D_DIM + d] = silu_f(y);
    }
  }
}

extern "C" void kernel_launch(void* const* d_in, const int* in_sizes, int n_in,
                              void* d_out, int out_size, void* d_ws, size_t ws_size,
                              hipStream_t stream) {
  (void)in_sizes; (void)n_in; (void)out_size; (void)ws_size;
  const float* x  = (const float*)d_in[0];
  const float* w1 = (const float*)d_in[1];
  const float* w2 = (const float*)d_in[2];
  const float* b2 = (const float*)d_in[3];
  float* out = (float*)d_out;

  __bf16* xb  = (__bf16*)d_ws;                        // 8192*2048
  __bf16* w1b = xb  + (size_t)M_DIM * D_DIM;          // 2048*2048
  __bf16* w2b = w1b + (size_t)DG_DIM * D_DIM;         // 8192*2048 (permuted)
  __bf16* hb  = w2b + (size_t)N2_DIM * DG_DIM;        // 8192*2048

  {
    int n4 = M_DIM * D_DIM / 4;
    cast_f32_bf16<<<(n4 + 255) / 256, 256, 0, stream>>>(x, xb, n4);
  }
  {
    int n4 = DG_DIM * D_DIM / 4;
    cast_f32_bf16<<<(n4 + 255) / 256, 256, 0, stream>>>(w1, w1b, n4);
  }
  {
    int n4 = N2_DIM * DG_DIM / 4;
    cast_permute_w2<<<(n4 + 255) / 256, 256, 0, stream>>>(w2, w2b, n4);
  }

  gemm1_silu<<<dim3(DG_DIM / 256, M_DIM / 256), 512, 0, stream>>>(xb, w1b, hb);
  gemm2_conv_silu<<<dim3(N2_DIM / 256, M_DIM / 256), 512, 0, stream>>>(
      hb, w2b, b2, x, out);
}

// Round 6
// 469.457 us; speedup vs baseline: 4.9736x; 4.9736x over previous
//
#include <hip/hip_runtime.h>
#include <cstdint>

// Problem constants
#define D_DIM  2048
#define T_DIM  4096
#define B_DIM  2
#define M_DIM  8192   // B*T
#define DG_DIM 2048
#define N2_DIM 8192   // D*W (W=4)
#define K_DIM  2048
#define NT_TILES (K_DIM / 64)   // 32 K-tiles of 64

typedef __bf16 bf16x8 __attribute__((ext_vector_type(8)));
typedef __bf16 bf16x4 __attribute__((ext_vector_type(4)));
typedef float  f32x4  __attribute__((ext_vector_type(4)));

__device__ __forceinline__ void gload_lds16(const void* g, void* l) {
  __builtin_amdgcn_global_load_lds(
      (__attribute__((address_space(1))) void*)g,
      (__attribute__((address_space(3))) void*)l, 16, 0, 0);
}

__device__ __forceinline__ float silu_f(float a) {
  return a / (1.f + __expf(-a));
}

// ---------------------------------------------------------------------------
// Casts
// ---------------------------------------------------------------------------
__global__ void cast_f32_bf16(const float* __restrict__ src,
                              __bf16* __restrict__ dst, int n4) {
  int i = blockIdx.x * blockDim.x + threadIdx.x;
  if (i >= n4) return;
  float4 v = ((const float4*)src)[i];
  bf16x4 o;
  o[0] = (__bf16)v.x; o[1] = (__bf16)v.y; o[2] = (__bf16)v.z; o[3] = (__bf16)v.w;
  ((bf16x4*)dst)[i] = o;
}

// w2 row-permutation: GEMM column c = n0 + wn*16 + j*64 + ln holds original
// row k = 4*d + j with d = 64*(c>>8) + 16*wn + ln, so each lane's 4
// j-fragments are the 4 taps of one d.
__global__ void cast_permute_w2(const float* __restrict__ src,
                                __bf16* __restrict__ dst, int n4) {
  int i = blockIdx.x * blockDim.x + threadIdx.x;
  if (i >= n4) return;
  const int row = i >> 9;            // dest row c (512 float4 per row of 2048)
  const int pos = i & 511;
  const int blk = row >> 8;          // 256-col tile
  const int cw  = row & 255;
  const int j   = cw >> 6;           // tap
  const int wn  = (cw >> 4) & 3;
  const int ln  = cw & 15;
  const int d   = blk * 64 + wn * 16 + ln;
  const int k   = 4 * d + j;         // original w2 row
  float4 v = ((const float4*)src)[(size_t)k * 512 + pos];
  bf16x4 o;
  o[0] = (__bf16)v.x; o[1] = (__bf16)v.y; o[2] = (__bf16)v.z; o[3] = (__bf16)v.w;
  ((bf16x4*)dst)[i] = o;
}

// ---------------------------------------------------------------------------
// 256x256 tile, BK=64, 8 waves (2M x 4N interleaved).  R6 structure:
// ONE barrier per K-tile + IN-PLACE fragment rotation (no register doubling;
// R5's double-buffered Frags spilled 8 GB of scratch).
//
// Quadrant order Q1(aL,b0) Q2(aH,b0) Q4(aH,b1) Q3(aL,b1).  Fragment deaths:
// b0 after Q2, aH after Q4, aL[i] per-group inside Q3, b1 after Q3.  Tile
// t+1's fragments are read into the SAME registers right after death, in
// 4-8-wide bursts between 16-MFMA clusters (reads fly under MFMA shadow):
//   Q1 | stage t+2 (8 gloads) | Q2 | rd b0' | Q4 | rd aH' |
//   Q3 interleaved with rd aL'[i] | rd b1' | lgkm(0) vm(0) barrier
// End-of-body sync does triple duty: lgkm(0) = t+1 frag reads landed (WAR
// vs next body's stages of t+3 into region t+1); vm(0) = own stages of t+2
// retired (issued ~2800 cyc earlier - free); barrier publishes t+2 to all
// waves and fences region reuse.  RAW for the t+1 reads: t+1 was staged in
// body t-1 and published by ITS end-of-body sync.  Clamped tail stages
// (s>=32) overwrite only post-read regions; body 31's t+1-reads pull
// clamped garbage into dead registers (never consumed).
// NOTE (R2): natural dispatch only - XCD swizzle doubled FETCH (252->600MB).
// NOTE (R5): fragment live-set must stay ~one tile (~96 VGPR) or it spills.
// ---------------------------------------------------------------------------

__device__ __forceinline__ void stage_unit(const __bf16* src, __bf16* sX,
                                           int s, int hf, int lq0) {
  const int k0 = (s < NT_TILES) ? (s * 64) : 0;       // clamp keeps vmcnt exact
  __bf16* dst = sX + ((s & 1) * 2 + hf) * 8192;
  const size_t goff = (size_t)hf * 128 * K_DIM + k0;
  gload_lds16(src + goff, dst + lq0);
  gload_lds16(src + goff + (size_t)64 * K_DIM, dst + lq0 + 4096);
}

__device__ __forceinline__ void read4(bf16x8 dst[4][2], const __bf16* base,
                                      const int off[4][2]) {
#pragma unroll
  for (int i = 0; i < 4; i++) {
    dst[i][0] = *(const bf16x8*)(base + off[i][0]);
    dst[i][1] = *(const bf16x8*)(base + off[i][1]);
  }
}

__device__ __forceinline__ void read2(bf16x8 dst[2][2], const __bf16* base,
                                      const int off[2][2]) {
#pragma unroll
  for (int j = 0; j < 2; j++) {
    dst[j][0] = *(const bf16x8*)(base + off[j][0]);
    dst[j][1] = *(const bf16x8*)(base + off[j][1]);
  }
}

__device__ __forceinline__ void mmaq(f32x4 acc[8][4], int ib, int jb,
                                     const bf16x8 a[4][2], const bf16x8 b[2][2]) {
  __builtin_amdgcn_s_setprio(1);
#pragma unroll
  for (int kk = 0; kk < 2; kk++)
#pragma unroll
    for (int i = 0; i < 4; i++)
#pragma unroll
      for (int j = 0; j < 2; j++)
        acc[ib + i][jb + j] = __builtin_amdgcn_mfma_f32_16x16x32_bf16(
            a[i][kk], b[j][kk], acc[ib + i][jb + j], 0, 0, 0);
  __builtin_amdgcn_s_setprio(0);
}

// One K-tile body.  Fragments rotate in place: entering with frags(t), all
// reads retarget them to frags(t+1) from parity region (nA,nB).
__device__ __forceinline__ void body_fn(f32x4 acc[8][4],
    bf16x8 aL[4][2], bf16x8 aH[4][2], bf16x8 b0[2][2], bf16x8 b1[2][2],
    const __bf16* nA, const __bf16* nB,
    const __bf16* a_src, const __bf16* b_src,
    __bf16* sA, __bf16* sB, int s2, int lq0,
    const int aoff[4][2], const int boff[2][2]) {
  // Q1 (aL, b0)
  mmaq(acc, 0, 0, aL, b0);
  __builtin_amdgcn_sched_barrier(0);
  // stage tile t+2 (8 loads, issue-only; region t parity — frags(t) already
  // in regs, reads completed in body t-1)
  stage_unit(a_src, sA, s2, 0, lq0);
  stage_unit(a_src, sA, s2, 1, lq0);
  stage_unit(b_src, sB, s2, 0, lq0);
  stage_unit(b_src, sB, s2, 1, lq0);
  __builtin_amdgcn_sched_barrier(0);
  // Q2 (aH, b0) — b0 dies
  mmaq(acc, 4, 0, aH, b0);
  __builtin_amdgcn_sched_barrier(0);
  read2(b0, nB, boff);                    // b0 <- tile t+1
  __builtin_amdgcn_sched_barrier(0);
  // Q4 (aH, b1) — aH dies
  mmaq(acc, 4, 2, aH, b1);
  __builtin_amdgcn_sched_barrier(0);
  read4(aH, nA + 8192, aoff);             // aH <- tile t+1
  __builtin_amdgcn_sched_barrier(0);
  // Q3 (aL, b1) interleaved: after group i, aL[i] dies -> reload from t+1
  __builtin_amdgcn_s_setprio(1);
#pragma unroll
  for (int i = 0; i < 4; i++) {
#pragma unroll
    for (int kk = 0; kk < 2; kk++)
#pragma unroll
      for (int j = 0; j < 2; j++)
        acc[i][2 + j] = __builtin_amdgcn_mfma_f32_16x16x32_bf16(
            aL[i][kk], b1[j][kk], acc[i][2 + j], 0, 0, 0);
    aL[i][0] = *(const bf16x8*)(nA + aoff[i][0]);   // aL[i] <- tile t+1
    aL[i][1] = *(const bf16x8*)(nA + aoff[i][1]);
  }
  __builtin_amdgcn_s_setprio(0);
  __builtin_amdgcn_sched_barrier(0);
  read2(b1, nB + 8192, boff);             // b1 <- tile t+1
  // Triple-duty sync (see header comment).
  asm volatile("s_waitcnt lgkmcnt(0)" ::: "memory");
  asm volatile("s_waitcnt vmcnt(0)" ::: "memory");
  __builtin_amdgcn_sched_barrier(0);
  __builtin_amdgcn_s_barrier();
  __builtin_amdgcn_sched_barrier(0);
}

__device__ __forceinline__ void gemm_core(const __bf16* __restrict__ A,
                                          const __bf16* __restrict__ B,
                                          int m0, int n0,
                                          __bf16* sA, __bf16* sB,
                                          f32x4 acc[8][4]) {
  constexpr int K = K_DIM;
  const int t    = threadIdx.x;       // 0..511
  const int lane = t & 63;
  const int wv   = t >> 6;
  const int wm   = wv >> 2;           // 0..1
  const int wn   = wv & 3;            // 0..3
  const int ln   = lane & 15, qd = lane >> 4;

  // Staging source: linear LDS dest chunk q = t; pre-swizzled global chunk
  // = (q&7) ^ (row&7).  Second gload per unit folded into stage_unit.
  const __bf16 *a_src, *b_src;
  int lq0;
  {
    int q = t, row = q >> 3, cg = (q & 7) ^ (row & 7);
    a_src = A + (size_t)(m0 + row) * K + cg * 8;
    b_src = B + (size_t)(n0 + row) * K + cg * 8;
    lq0 = q * 8;
  }

  // Fragment LDS offsets within a half-region (same for both halves).
  int aoff[4][2], boff[2][2];
#pragma unroll
  for (int i = 0; i < 4; i++)
#pragma unroll
    for (int kk = 0; kk < 2; kk++) {
      const int row = wm * 16 + i * 32 + ln;
      aoff[i][kk] = row * 64 + (((kk * 4 + qd) ^ (row & 7)) << 3);
    }
#pragma unroll
  for (int j = 0; j < 2; j++)
#pragma unroll
    for (int kk = 0; kk < 2; kk++) {
      const int row = j * 64 + wn * 16 + ln;
      boff[j][kk] = row * 64 + (((kk * 4 + qd) ^ (row & 7)) << 3);
    }

  const __bf16* A_p0 = sA;           const __bf16* A_p1 = sA + 16384;
  const __bf16* B_p0 = sB;           const __bf16* B_p1 = sB + 16384;

  bf16x8 aL[4][2], aH[4][2], b0[2][2], b1[2][2];

  // Prologue: stage tile0 + tile1 fully (16 loads), publish, read frags(0).
  stage_unit(a_src, sA, 0, 0, lq0);
  stage_unit(a_src, sA, 0, 1, lq0);
  stage_unit(b_src, sB, 0, 0, lq0);
  stage_unit(b_src, sB, 0, 1, lq0);
  stage_unit(a_src, sA, 1, 0, lq0);
  stage_unit(a_src, sA, 1, 1, lq0);
  stage_unit(b_src, sB, 1, 0, lq0);
  stage_unit(b_src, sB, 1, 1, lq0);
  asm volatile("s_waitcnt vmcnt(8)" ::: "memory");   // tile0 fully landed
  __builtin_amdgcn_s_barrier();
  __builtin_amdgcn_sched_barrier(0);
  read4(aL, A_p0, aoff);
  read4(aH, A_p0 + 8192, aoff);
  read2(b0, B_p0, boff);
  read2(b1, B_p0 + 8192, boff);
  asm volatile("s_waitcnt lgkmcnt(0)" ::: "memory");
  __builtin_amdgcn_sched_barrier(0);
  __builtin_amdgcn_s_barrier();      // protect tile0 region from body-0 stages
  __builtin_amdgcn_sched_barrier(0);

  for (int it = 0; it < NT_TILES / 2; ++it) {
    // body t = 2*it   (tile parity 0): reads frags <- tile t+1 (parity 1)
    body_fn(acc, aL, aH, b0, b1, A_p1, B_p1, a_src, b_src, sA, sB,
            2 * it + 2, lq0, aoff, boff);
    // body t = 2*it+1 (parity 1): reads frags <- tile t+2 (parity 0)
    body_fn(acc, aL, aH, b0, b1, A_p0, B_p0, a_src, b_src, sA, sB,
            2 * it + 3, lq0, aoff, boff);
  }
  // Drain any clamped tail staging before LDS is reused/deallocated.
  asm volatile("s_waitcnt vmcnt(0)" ::: "memory");
}

// ---------------------------------------------------------------------------
// GEMM1: H = silu(x_bf16 @ w1_bf16^T).  Natural dispatch (column-per-XCD).
// ---------------------------------------------------------------------------
__global__ __launch_bounds__(512) void gemm1_silu(
    const __bf16* __restrict__ A, const __bf16* __restrict__ B,
    __bf16* __restrict__ H) {
  __shared__ __bf16 sA[4 * 8192];
  __shared__ __bf16 sB[4 * 8192];
  const int m0 = blockIdx.y * 256, n0 = blockIdx.x * 256;
  f32x4 acc[8][4] = {};
  gemm_core(A, B, m0, n0, sA, sB, acc);

  const int lane = threadIdx.x & 63;
  const int wv   = threadIdx.x >> 6;
  const int wm   = wv >> 2, wn = wv & 3;
  const int ln   = lane & 15, qd = lane >> 4;
#pragma unroll
  for (int i = 0; i < 8; i++) {
    const int row0 = m0 + wm * 16 + i * 32 + qd * 4;
#pragma unroll
    for (int j = 0; j < 4; j++) {
      const int col = n0 + wn * 16 + j * 64 + ln;
#pragma unroll
      for (int r = 0; r < 4; r++)
        H[(size_t)(row0 + r) * DG_DIM + col] = (__bf16)silu_f(acc[i][j][r]);
    }
  }
}

// ---------------------------------------------------------------------------
// GEMM2 + fused causal depthwise conv + silu.  B = permuted w2; lane owns
// d = (n0>>2) + wn*16 + ln; its 4 j-fragments are taps w=0..3 of that d.
// Natural dispatch (R2 lesson).
// ---------------------------------------------------------------------------
__global__ __launch_bounds__(512) void gemm2_conv_silu(
    const __bf16* __restrict__ A, const __bf16* __restrict__ B,
    const float* __restrict__ b2, const float* __restrict__ x,
    float* __restrict__ out) {
  __shared__ __bf16 sA[4 * 8192];
  __shared__ __bf16 sB[4 * 8192];
  const int m0 = blockIdx.y * 256, n0 = blockIdx.x * 256;
  f32x4 acc[8][4] = {};
  gemm_core(A, B, m0, n0, sA, sB, acc);

  const int lane = threadIdx.x & 63;
  const int wv   = threadIdx.x >> 6;
  const int wm   = wv >> 2, wn = wv & 3;
  const int ln   = lane & 15, qd = lane >> 4;

  const int d = (n0 >> 2) + wn * 16 + ln;
  const float4 bias = *(const float4*)(b2 + 4 * d);

#pragma unroll
  for (int i = 0; i < 8; i++) {
    const int m_base = m0 + wm * 16 + i * 32 + qd * 4;   // + r
    const int b  = m_base >> 12;                          // T=4096
    const int tb = m_base & 4095;
    // taps: x[b, tb + s - 3, d] for s = r + j in [0,6]
    float xv[7];
#pragma unroll
    for (int s = 0; s < 7; s++) {
      const int tp = tb + s - 3;
      xv[s] = (tp >= 0) ? x[((size_t)((b << 12) + tp)) * D_DIM + d] : 0.f;
    }
#pragma unroll
    for (int r = 0; r < 4; r++) {
      float y = (acc[i][0][r] + bias.x) * xv[r + 0]
              + (acc[i][1][r] + bias.y) * xv[r + 1]
              + (acc[i][2][r] + bias.z) * xv[r + 2]
              + (acc[i][3][r] + bias.w) * xv[r + 3];
      out[(size_t)(m_base + r) * D_DIM + d] = silu_f(y);
    }
  }
}

extern "C" void kernel_launch(void* const* d_in, const int* in_sizes, int n_in,
                              void* d_out, int out_size, void* d_ws, size_t ws_size,
                              hipStream_t stream) {
  (void)in_sizes; (void)n_in; (void)out_size; (void)ws_size;
  const float* x  = (const float*)d_in[0];
  const float* w1 = (const float*)d_in[1];
  const float* w2 = (const float*)d_in[2];
  const float* b2 = (const float*)d_in[3];
  float* out = (float*)d_out;

  __bf16* xb  = (__bf16*)d_ws;                        // 8192*2048
  __bf16* w1b = xb  + (size_t)M_DIM * D_DIM;          // 2048*2048
  __bf16* w2b = w1b + (size_t)DG_DIM * D_DIM;         // 8192*2048 (permuted)
  __bf16* hb  = w2b + (size_t)N2_DIM * DG_DIM;        // 8192*2048

  {
    int n4 = M_DIM * D_DIM / 4;
    cast_f32_bf16<<<(n4 + 255) / 256, 256, 0, stream>>>(x, xb, n4);
  }
  {
    int n4 = DG_DIM * D_DIM / 4;
    cast_f32_bf16<<<(n4 + 255) / 256, 256, 0, stream>>>(w1, w1b, n4);
  }
  {
    int n4 = N2_DIM * DG_DIM / 4;
    cast_permute_w2<<<(n4 + 255) / 256, 256, 0, stream>>>(w2, w2b, n4);
  }

  gemm1_silu<<<dim3(DG_DIM / 256, M_DIM / 256), 512, 0, stream>>>(xb, w1b, hb);
  gemm2_conv_silu<<<dim3(N2_DIM / 256, M_DIM / 256), 512, 0, stream>>>(
      hb, w2b, b2, x, out);
}